// Round 2
// baseline (76.419 us; speedup 1.0000x reference)
//
#include <hip/hip_runtime.h>

// GNNHierarchyModel: complete-graph GCN (N=1024) collapses to rank-1.
//   s = (1/1024) * sum_i emb[y[i]]          [64]
//   h = relu(s @ W1 + b1)                   [128]
//   o = h @ W2 + b2                         [64]
//   out[i,:] = o  for all 1024 rows         [1024,64]
// norm == 1/1024 uniform (complete graph + self loops, deg==1024 everywhere),
// so edge_index (d_in[1]) is unused.
//
// Storage dtype of the float tensors (emb/W1/b1/W2/b2 and out) is detected at
// runtime: bf16 (2-byte) vs fp32 (4-byte). Evidence from R1: stub and a pure
// bf16-interpretation kernel gave identical absmax == max|ref| => fp32 storage
// suspected; detection makes either correct.

#define NTHREADS 256
#define NBLOCKS 16

__device__ __forceinline__ float b2f(unsigned short u) {
    union { unsigned int i; float f; } v;
    v.i = ((unsigned int)u) << 16;
    return v.f;
}

// fp32 -> bf16 round-to-nearest-even
__device__ __forceinline__ unsigned short f2b(float f) {
    unsigned int x = __float_as_uint(f);
    unsigned int r = (x + 0x7fffu + ((x >> 16) & 1u)) >> 16;
    return (unsigned short)r;
}

__global__ __launch_bounds__(NTHREADS) void gnn_fused(
    const int* __restrict__ y,
    const void* __restrict__ emb,
    const void* __restrict__ W1,
    const void* __restrict__ b1,
    const void* __restrict__ W2,
    const void* __restrict__ b2,
    void* __restrict__ out)
{
    __shared__ __align__(16) float red[32][64];  // partial column sums (also reused as scratch)
    __shared__ float s[64];
    __shared__ float h[128];
    __shared__ __align__(16) float o[64];
    __shared__ int flag;

    const int tid = threadIdx.x;

    // ---- Dtype detection on W1 (8192 elements, |x|~0.125 scale, none ~0).
    // bf16 storage: even ushorts are bf16 values, exponent field in [90,140]
    //   for essentially all 64 samples.
    // fp32 storage: even ushorts are low mantissa halves -> random exponent
    //   (~20% hit) or exactly 0 if values were bf16-rounded (0% hit).
    if (tid == 0) {
        const unsigned short* p = (const unsigned short*)W1;
        int cnt = 0;
        #pragma unroll
        for (int i = 0; i < 64; ++i) {
            const int e = (p[2 * i] >> 7) & 0xFF;
            cnt += (e >= 90 && e <= 140) ? 1 : 0;
        }
        flag = (cnt >= 48) ? 1 : 0;
    }
    __syncthreads();
    const bool isbf = (flag != 0);   // block-uniform branch

    const int g  = tid >> 3;   // row group 0..31
    const int o8 = tid & 7;    // 8-column chunk 0..7

    // ---- Phase 1: s = (1/1024) * sum_i emb[y[i]]
    // 8 lanes cover one 64-col row (8 cols each); each thread does 32 rows.
    float acc[8];
    #pragma unroll
    for (int k = 0; k < 8; ++k) acc[k] = 0.f;

    if (isbf) {
        const unsigned short* pe = (const unsigned short*)emb;
        for (int it = 0; it < 32; ++it) {
            const int r = y[(it << 5) + g];
            const uint4 v = *(const uint4*)(pe + (r << 6) + (o8 << 3));
            const unsigned short* us = (const unsigned short*)&v;
            #pragma unroll
            for (int k = 0; k < 8; ++k) acc[k] += b2f(us[k]);
        }
    } else {
        const float* pe = (const float*)emb;
        for (int it = 0; it < 32; ++it) {
            const int r = y[(it << 5) + g];
            const float* pr = pe + (r << 6) + (o8 << 3);
            const float4 v0 = *(const float4*)pr;
            const float4 v1 = *(const float4*)(pr + 4);
            acc[0] += v0.x; acc[1] += v0.y; acc[2] += v0.z; acc[3] += v0.w;
            acc[4] += v1.x; acc[5] += v1.y; acc[6] += v1.z; acc[7] += v1.w;
        }
    }
    #pragma unroll
    for (int k = 0; k < 8; ++k) red[g][(o8 << 3) + k] = acc[k];
    __syncthreads();

    if (tid < 64) {
        float t = 0.f;
        #pragma unroll
        for (int gg = 0; gg < 32; ++gg) t += red[gg][tid];
        s[tid] = t * (1.0f / 1024.0f);
    }
    __syncthreads();

    // ---- Phase 2: h = relu(s @ W1 + b1); one thread per hidden unit,
    // consecutive lanes read consecutive W1 addresses (coalesced).
    if (tid < 128) {
        float a = isbf ? b2f(((const unsigned short*)b1)[tid])
                       : ((const float*)b1)[tid];
        if (isbf) {
            const unsigned short* pw = (const unsigned short*)W1;
            #pragma unroll
            for (int k = 0; k < 64; ++k) a = fmaf(s[k], b2f(pw[k * 128 + tid]), a);
        } else {
            const float* pw = (const float*)W1;
            #pragma unroll
            for (int k = 0; k < 64; ++k) a = fmaf(s[k], pw[k * 128 + tid], a);
        }
        h[tid] = fmaxf(a, 0.f);
    }
    __syncthreads();

    // ---- Phase 3: o = h @ W2 + b2; one thread per output column.
    if (tid < 64) {
        float a = isbf ? b2f(((const unsigned short*)b2)[tid])
                       : ((const float*)b2)[tid];
        if (isbf) {
            const unsigned short* pw = (const unsigned short*)W2;
            #pragma unroll
            for (int k = 0; k < 128; ++k) a = fmaf(h[k], b2f(pw[k * 64 + tid]), a);
        } else {
            const float* pw = (const float*)W2;
            #pragma unroll
            for (int k = 0; k < 128; ++k) a = fmaf(h[k], pw[k * 64 + tid], a);
        }
        o[tid] = a;
    }
    __syncthreads();

    // ---- Phase 4: broadcast o to this block's 64-row slice of out.
    if (isbf) {
        // pack o into bf16 bits in shared scratch (reuse red)
        unsigned short* obf = (unsigned short*)&red[0][0];
        if (tid < 64) obf[tid] = f2b(o[tid]);
        __syncthreads();
        const uint4* ov = (const uint4*)obf;       // 8 x uint4 = 64 bf16
        uint4* po = (uint4*)out;                   // 8192 uint4 total
        const int base = (int)blockIdx.x * (8192 / NBLOCKS);
        #pragma unroll
        for (int i = tid; i < 8192 / NBLOCKS; i += NTHREADS)
            po[base + i] = ov[i & 7];              // base % 8 == 0
    } else {
        const float4* ov = (const float4*)o;       // 16 x float4 = 64 f32
        float4* po = (float4*)out;                 // 16384 float4 total
        const int base = (int)blockIdx.x * (16384 / NBLOCKS);
        #pragma unroll
        for (int i = tid; i < 16384 / NBLOCKS; i += NTHREADS)
            po[base + i] = ov[i & 15];             // base % 16 == 0
    }
}

extern "C" void kernel_launch(void* const* d_in, const int* in_sizes, int n_in,
                              void* d_out, int out_size, void* d_ws, size_t ws_size,
                              hipStream_t stream) {
    const int* y   = (const int*)d_in[0];
    // d_in[1] = edge_index: unused (complete graph => norm == 1/1024 uniform)
    const void* emb = d_in[2];
    const void* W1  = d_in[3];
    const void* b1  = d_in[4];
    const void* W2  = d_in[5];
    const void* b2  = d_in[6];

    gnn_fused<<<NBLOCKS, NTHREADS, 0, stream>>>(y, emb, W1, b1, W2, b2, d_out);
}

// Round 3
// 74.847 us; speedup vs baseline: 1.0210x; 1.0210x over previous
//
#include <hip/hip_runtime.h>

// GNNHierarchyModel: complete-graph GCN (N=1024) collapses to rank-1.
//   s = (1/1024) * sum_i emb[y[i]]          [64]
//   h = relu(s @ W1 + b1)                   [128]
//   o = h @ W2 + b2                         [64]
//   out[i,:] = o  for all 1024 rows         [1024,64] fp32
//
// Why: complete graph + self-loops => deg == 1024 for every node =>
// norm == 1/1024 uniform, and segment_sum over all-pairs edges makes every
// output row the same mean. edge_index (d_in[1]) is therefore unused.
//
// Storage dtype: fp32 (verified R2 — fp32 path gives absmax 0.0; bf16
// interpretation in R0/R1 gave garbage). Runtime dtype detection removed
// (it cost a serial 64-load chain + barrier before any real work).

#define NTHREADS 256
#define NBLOCKS 16

__global__ __launch_bounds__(NTHREADS) void gnn_fused(
    const int* __restrict__ y,
    const float* __restrict__ emb,
    const float* __restrict__ W1,
    const float* __restrict__ b1,
    const float* __restrict__ W2,
    const float* __restrict__ b2,
    float4* __restrict__ out)   // 1024*64 fp32 = 16384 float4
{
    __shared__ __align__(16) float red[32][64];  // per-row-group partial sums
    __shared__ float s[64];
    __shared__ float h[128];
    __shared__ __align__(16) float o[64];

    const int tid = threadIdx.x;
    const int g   = tid >> 3;   // row group 0..31
    const int o8  = tid & 7;    // 8-column chunk 0..7

    // ---- Phase 1: s = (1/1024) * sum_i emb[y[i]]
    // Each block computes it redundantly (emb = 256 KB, L2-resident).
    // 8 lanes cover one 64-col row (8 cols each, 2x float4); each thread
    // accumulates 32 gathered rows in fp32.
    float acc[8];
    #pragma unroll
    for (int k = 0; k < 8; ++k) acc[k] = 0.f;

    for (int it = 0; it < 32; ++it) {
        const int r = y[(it << 5) + g];          // broadcast within 8-lane group
        const float* pr = emb + (r << 6) + (o8 << 3);
        const float4 v0 = *(const float4*)pr;
        const float4 v1 = *(const float4*)(pr + 4);
        acc[0] += v0.x; acc[1] += v0.y; acc[2] += v0.z; acc[3] += v0.w;
        acc[4] += v1.x; acc[5] += v1.y; acc[6] += v1.z; acc[7] += v1.w;
    }
    #pragma unroll
    for (int k = 0; k < 8; ++k) red[g][(o8 << 3) + k] = acc[k];
    __syncthreads();

    if (tid < 64) {
        float t = 0.f;
        #pragma unroll
        for (int gg = 0; gg < 32; ++gg) t += red[gg][tid];
        s[tid] = t * (1.0f / 1024.0f);
    }
    __syncthreads();

    // ---- Phase 2: h = relu(s @ W1 + b1); one thread per hidden unit.
    // W1[k*128 + tid]: consecutive lanes -> consecutive addresses (coalesced).
    if (tid < 128) {
        float a = b1[tid];
        #pragma unroll
        for (int k = 0; k < 64; ++k) a = fmaf(s[k], W1[k * 128 + tid], a);
        h[tid] = fmaxf(a, 0.f);
    }
    __syncthreads();

    // ---- Phase 3: o = h @ W2 + b2; one thread per output column.
    if (tid < 64) {
        float a = b2[tid];
        #pragma unroll
        for (int k = 0; k < 128; ++k) a = fmaf(h[k], W2[k * 64 + tid], a);
        o[tid] = a;
    }
    __syncthreads();

    // ---- Phase 4: broadcast o to this block's 64-row slice of out.
    // 16384 float4 total / 16 blocks = 1024 per block; coalesced 16B stores.
    const float4* ov = (const float4*)o;         // 16 x float4 = 64 f32
    const int base = (int)blockIdx.x * (16384 / NBLOCKS);
    #pragma unroll
    for (int i = tid; i < 16384 / NBLOCKS; i += NTHREADS)
        out[base + i] = ov[i & 15];              // base % 16 == 0
}

extern "C" void kernel_launch(void* const* d_in, const int* in_sizes, int n_in,
                              void* d_out, int out_size, void* d_ws, size_t ws_size,
                              hipStream_t stream) {
    const int* y      = (const int*)d_in[0];
    // d_in[1] = edge_index: unused (complete graph => norm == 1/1024 uniform)
    const float* emb  = (const float*)d_in[2];
    const float* W1   = (const float*)d_in[3];
    const float* b1   = (const float*)d_in[4];
    const float* W2   = (const float*)d_in[5];
    const float* b2   = (const float*)d_in[6];

    gnn_fused<<<NBLOCKS, NTHREADS, 0, stream>>>(y, emb, W1, b1, W2, b2,
                                                (float4*)d_out);
}